// Round 14
// baseline (146.235 us; speedup 1.0000x reference)
//
#include <hip/hip_runtime.h>

// Problem constants (from reference): B=8, C=3, H=512, W=960
#define Bc 8
#define Cc 3
#define Hc 512
#define Wc 960
#define HWc (Hc * Wc)          // 491520
#define NPIX (Bc * HWc)        // 3932160
#define NTOT (Bc * Cc * HWc)   // 11796480
#define PPB 1024               // pixels per block (256 threads x 4)
#define BPB (HWc / PPB)        // 480 blocks per batch
#define NBLK (NPIX / PPB)      // 3840 blocks

typedef float f4a __attribute__((ext_vector_type(4), aligned(16)));

__global__ __launch_bounds__(256) void warp_loss_kernel(
    const float* __restrict__ disp,
    const float* __restrict__ left,
    const float* __restrict__ right,
    float* __restrict__ out,      // out[0]=loss (finalize), out[1..] = img_warp_mask
    double* __restrict__ ws)      // ws[0..NBLK) per-block partials
{
    __shared__ f4a lds4[Cc][PPB / 4];   // 12 KB staging: [channel][f4 index]
    __shared__ double wsum[4];

    const int t   = threadIdx.x;
    const int bid = blockIdx.x;
    const int b   = bid / BPB;
    const int P   = (bid - b * BPB) * PPB;   // first pixel of this block
    const int pix = P + 4 * t;               // first pixel of this thread's chunk
    const int x   = pix % Wc;                // Wc%4==0 -> chunk never straddles a row

    // disp[b,0,y,x..x+3] and disp[b,1,y,x..x+3] — 16B aligned
    const size_t dbase = (size_t)b * 2 * HWc + pix;
    const f4a d0v = *(const f4a*)(disp + dbase);
    const f4a d1v = *(const f4a*)(disp + dbase + HWc);

    float v0[4], v1[4], v2[4];
    float local = 0.0f;

    const float* rb = right + (size_t)b * Cc * HWc;
    const float* lb = left  + (size_t)b * Cc * HWc;

    #pragma unroll
    for (int e = 0; e < 4; ++e) {
        const float d0 = d0v[e];
        const float d1 = d1v[e];
        const float xe = (float)(x + e);

        // vgrid = arange(W) - disp; sampler treats it as normalized coords
        const float gx = xe - d0;
        const float gy = xe - d1;
        const float ix = ((gx + 1.0f) * (float)Wc - 1.0f) * 0.5f;
        const float iy = ((gy + 1.0f) * (float)Hc - 1.0f) * 0.5f;

        const float x0f = floorf(ix);
        const float y0f = floorf(iy);
        const float x1f = x0f + 1.0f;
        const float y1f = y0f + 1.0f;
        const float wx1 = ix - x0f, wx0 = 1.0f - wx1;
        const float wy1 = iy - y0f, wy0 = 1.0f - wy1;

        const bool vx0 = (x0f >= 0.0f) & (x0f <= (float)(Wc - 1));
        const bool vx1 = (x1f >= 0.0f) & (x1f <= (float)(Wc - 1));
        const bool vy0 = (y0f >= 0.0f) & (y0f <= (float)(Hc - 1));
        const bool vy1 = (y1f >= 0.0f) & (y1f <= (float)(Hc - 1));

        const float m00 = (vx0 && vy0) ? 1.0f : 0.0f;
        const float m10 = (vx1 && vy0) ? 1.0f : 0.0f;
        const float m01 = (vx0 && vy1) ? 1.0f : 0.0f;
        const float m11 = (vx1 && vy1) ? 1.0f : 0.0f;

        const float w00 = wx0 * wy0, w10 = wx1 * wy0;
        const float w01 = wx0 * wy1, w11 = wx1 * wy1;

        const float maskv = m00 * w00 + m10 * w10 + m01 * w01 + m11 * w11;

        if (maskv < 0.999f) {
            v0[e] = 0.0f; v1[e] = 0.0f; v2[e] = 0.0f;
        } else {
            const int x0 = min(max((int)x0f, 0), Wc - 1);
            const int x1 = min(max((int)x1f, 0), Wc - 1);
            const int y0 = min(max((int)y0f, 0), Hc - 1);
            const int y1 = min(max((int)y1f, 0), Hc - 1);
            const int rem = pix + e;

            #pragma unroll
            for (int c = 0; c < Cc; ++c) {
                const float* rc = rb + c * HWc;
                const float s00 = (m00 != 0.0f) ? rc[y0 * Wc + x0] : 0.0f;
                const float s10 = (m10 != 0.0f) ? rc[y0 * Wc + x1] : 0.0f;
                const float s01 = (m01 != 0.0f) ? rc[y1 * Wc + x0] : 0.0f;
                const float s11 = (m11 != 0.0f) ? rc[y1 * Wc + x1] : 0.0f;
                const float val = s00 * w00 + s10 * w10 + s01 * w01 + s11 * w11;
                if (c == 0) v0[e] = val;
                if (c == 1) v1[e] = val;
                if (c == 2) v2[e] = val;
                local += fabsf(val - lb[c * HWc + rem]);
            }
        }
    }

    // stage to LDS (aligned ds_write_b128)
    lds4[0][t] = (f4a){v0[0], v0[1], v0[2], v0[3]};
    lds4[1][t] = (f4a){v1[0], v1[1], v1[2], v1[3]};
    lds4[2][t] = (f4a){v2[0], v2[1], v2[2], v2[3]};

    // wave (64-lane) reduction for the loss
    #pragma unroll
    for (int off = 32; off > 0; off >>= 1)
        local += __shfl_down(local, off, 64);
    if ((t & 63) == 0) wsum[t >> 6] = (double)local;

    __syncthreads();

    // store phase: segment base ≡ 1 (mod 4) in out-elements; shift by 3 so
    // every bulk store is a 16B-aligned global_store_dwordx4.
    float* ob = out + 1 + (size_t)b * Cc * HWc + P;
    #pragma unroll
    for (int c = 0; c < Cc; ++c) {
        float* seg = ob + c * HWc;
        if (t < 255) {
            const f4a va = lds4[c][t];
            const f4a vb = lds4[c][t + 1];
            const f4a o4 = (f4a){va[3], vb[0], vb[1], vb[2]};
            *(f4a*)(seg + 3 + 4 * t) = o4;     // elem index ≡ 0 mod 4: aligned
        } else {
            const float* lf = (const float*)&lds4[c][0];
            seg[0]    = lf[0];
            seg[1]    = lf[1];
            seg[2]    = lf[2];
            seg[1023] = lf[1023];
        }
    }

    if (t == 0)
        ws[bid] = wsum[0] + wsum[1] + wsum[2] + wsum[3];
}

__global__ __launch_bounds__(1024) void finalize_kernel(
    const double* __restrict__ ws, float* __restrict__ out)
{
    double s = 0.0;
    for (int i = threadIdx.x; i < NBLK; i += 1024)
        s += ws[i];

    #pragma unroll
    for (int off = 32; off > 0; off >>= 1)
        s += __shfl_down(s, off, 64);

    __shared__ double l[16];
    if ((threadIdx.x & 63) == 0) l[threadIdx.x >> 6] = s;
    __syncthreads();
    if (threadIdx.x == 0) {
        double t = 0.0;
        #pragma unroll
        for (int i = 0; i < 16; ++i) t += l[i];
        out[0] = (float)(t / (double)NTOT);
    }
}

extern "C" void kernel_launch(void* const* d_in, const int* in_sizes, int n_in,
                              void* d_out, int out_size, void* d_ws, size_t ws_size,
                              hipStream_t stream) {
    const float* disp  = (const float*)d_in[0];
    const float* left  = (const float*)d_in[1];
    const float* right = (const float*)d_in[2];
    float* out = (float*)d_out;
    double* ws = (double*)d_ws;

    warp_loss_kernel<<<NBLK, 256, 0, stream>>>(disp, left, right, out, ws);
    finalize_kernel<<<1, 1024, 0, stream>>>(ws, out);
}